// Round 4
// baseline (78.319 us; speedup 1.0000x reference)
//
#include <hip/hip_runtime.h>

// Problem constants (fixed by setup_inputs): N=512 anchors, D=128 dims, K=16.
constexpr int NN = 512;
constexpr int DD = 128;
constexpr int KK = 16;
constexpr int GG = 2;           // anchors per block (one yad sweep serves both)
constexpr int NB = NN / GG;     // 256 blocks -> one per CU, all co-resident
constexpr int NT = 256;         // 4 waves: each thread owns 2 rows, reusing yi
                                // LDS chunks across both rows (halves ds_read
                                // issue pressure vs 512-thread/1-row variant)
#define ALPHA 0.1f
#define MAGIC 0x5CA1AB1Eu       // != 0xAAAAAAAA harness poison, != 0

__global__ __launch_bounds__(NT) void area_loss_fused(
    const float* __restrict__ wid,
    const float* __restrict__ ken,
    const float* __restrict__ lrg,
    const float* __restrict__ sml,
    const float* __restrict__ yad,
    const int*   __restrict__ x,
    float*       __restrict__ out,
    float*       __restrict__ partial,   // d_ws
    unsigned*    __restrict__ flags)     // d_ws + NB floats
{
    __shared__ float    yi[GG][DD];        // the block's 2 anchor rows
    __shared__ float    d2[GG][NN];        // distances anchor->all j
    __shared__ unsigned mask[GG][NN / 32]; // membership bitsets
    __shared__ int      xl[GG][KK];        // staged x rows
    __shared__ float    posd[GG][KK];
    __shared__ int      pcnt[GG];
    __shared__ float    wsum[NT / 64];

    const int b = blockIdx.x;
    const int t = threadIdx.x;
    const int ibase = b * GG;

    // Stage anchors (float4), x rows; init masks/counters.
    if (t < GG * DD / 4)
        ((float4*)yi)[t] = ((const float4*)(yad + (size_t)ibase * DD))[t];
    if (t < GG * NN / 32) ((unsigned*)mask)[t] = 0u;
    if (t < GG * KK)      ((int*)xl)[t] = x[ibase * KK + t];
    if (t < GG)           pcnt[t] = 0;
    __syncthreads();

    // Membership bitmasks (duplicates collapse, matching reference scatter).
    if (t < GG * KK) {
        int a = t / KK;
        int j = xl[a][t % KK];
        atomicOr(&mask[a][j >> 5], 1u << (j & 31));
    }

    // Distances: thread t owns rows j=t and j=t+NT; each yi LDS chunk is
    // loaded once per c-iter and reused for both rows and both anchors.
    {
        const float4* r0 = (const float4*)(yad + (size_t)t * DD);
        const float4* r1 = (const float4*)(yad + (size_t)(t + NT) * DD);
        float a00 = 0.f, a01 = 0.f, a10 = 0.f, a11 = 0.f;
#pragma unroll
        for (int c = 0; c < DD / 4; ++c) {
            float4 v0 = r0[c];
            float4 v1 = r1[c];
            float4 y0 = ((const float4*)yi[0])[c];
            float4 y1 = ((const float4*)yi[1])[c];
            float e;
            e = v0.x - y0.x; a00 += e * e;
            e = v0.y - y0.y; a00 += e * e;
            e = v0.z - y0.z; a00 += e * e;
            e = v0.w - y0.w; a00 += e * e;
            e = v0.x - y1.x; a01 += e * e;
            e = v0.y - y1.y; a01 += e * e;
            e = v0.z - y1.z; a01 += e * e;
            e = v0.w - y1.w; a01 += e * e;
            e = v1.x - y0.x; a10 += e * e;
            e = v1.y - y0.y; a10 += e * e;
            e = v1.z - y0.z; a10 += e * e;
            e = v1.w - y0.w; a10 += e * e;
            e = v1.x - y1.x; a11 += e * e;
            e = v1.y - y1.y; a11 += e * e;
            e = v1.z - y1.z; a11 += e * e;
            e = v1.w - y1.w; a11 += e * e;
        }
        d2[0][t]      = a00;
        d2[1][t]      = a01;
        d2[0][t + NT] = a10;
        d2[1][t + NT] = a11;
    }
    __syncthreads();

    // Pos-set gather: first occurrence only (dedup), j != anchor.
    if (t < GG * KK) {
        int a = t / KK, e = t % KK;
        int j = xl[a][e];
        bool ok = (j != ibase + a);
        for (int q = 0; q < e && ok; ++q)
            if (xl[a][q] == j) ok = false;
        if (ok) {
            int p = atomicAdd(&pcnt[a], 1);
            posd[a][p] = d2[a][j];
        }
    }
    __syncthreads();

    float acc = 0.f;

    // Triplet hinge: thread t owns neg-candidates k=t and k=t+NT per anchor.
#pragma unroll
    for (int a = 0; a < GG; ++a) {
        const int ia = ibase + a;
        const int P  = pcnt[a];
#pragma unroll
        for (int h = 0; h < 2; ++h) {
            const int k = t + h * NT;
            if (k != ia && !((mask[a][k >> 5] >> (k & 31)) & 1u)) {
                float dk = d2[a][k];
                for (int p = 0; p < P; ++p)
                    acc += fmaxf(posd[a][p] - dk + ALPHA, 0.f);
            }
        }
    }

    // Hierarchical term: this block's GG rows = contiguous slice of GG*DD=256
    // floats; 256 threads -> one element each (coalesced dword loads).
    {
        size_t idx = (size_t)ibase * DD + t;
        float w = wid[idx], kk = ken[idx], l = lrg[idx], s = sml[idx];
        float y = ((float*)yi)[t];
        float p0 = w - kk, p1 = w - l, p2 = l - s, p3 = s - y;
        acc += p0 * p0 + p1 * p1 + p2 * p2 + p3 * p3;
    }

    // Block reduction: shuffle within wave-64, LDS across 4 waves.
    for (int off = 32; off; off >>= 1) acc += __shfl_down(acc, off, 64);
    if ((t & 63) == 0) wsum[t >> 6] = acc;
    __syncthreads();

    if (b != 0) {
        if (t == 0) {
            float s = wsum[0] + wsum[1] + wsum[2] + wsum[3];
            partial[b] = s;
            // Release: partial[b] visible device-wide before flag flips.
            __hip_atomic_store(&flags[b], MAGIC, __ATOMIC_RELEASE,
                               __HIP_MEMORY_SCOPE_AGENT);
        }
    } else {
        // Block 0: own sum, then gather the other 255 partials via flag spin.
        float mine = 0.f;
        if (t == 0) mine = wsum[0] + wsum[1] + wsum[2] + wsum[3];
        __syncthreads();  // t0 done with wsum before reuse

        float other = 0.f;
        if (t >= 1 && t < NB) {
            while (__hip_atomic_load(&flags[t], __ATOMIC_ACQUIRE,
                                     __HIP_MEMORY_SCOPE_AGENT) != MAGIC) {
                __builtin_amdgcn_s_sleep(1);
            }
            other = partial[t];
        }
        float tot = mine + other;
        for (int off = 32; off; off >>= 1) tot += __shfl_down(tot, off, 64);
        if ((t & 63) == 0) wsum[t >> 6] = tot;
        __syncthreads();
        if (t == 0) out[0] = wsum[0] + wsum[1] + wsum[2] + wsum[3];
    }
}

extern "C" void kernel_launch(void* const* d_in, const int* in_sizes, int n_in,
                              void* d_out, int out_size, void* d_ws, size_t ws_size,
                              hipStream_t stream) {
    const float* wid = (const float*)d_in[0];
    const float* ken = (const float*)d_in[1];
    const float* lrg = (const float*)d_in[2];
    const float* sml = (const float*)d_in[3];
    const float* yad = (const float*)d_in[4];
    const int*   x   = (const int*)d_in[5];
    float*    out     = (float*)d_out;
    float*    partial = (float*)d_ws;              // NB floats
    unsigned* flags   = (unsigned*)(partial + NB); // NB words; poison != MAGIC

    area_loss_fused<<<NB, NT, 0, stream>>>(wid, ken, lrg, sml, yad, x,
                                           out, partial, flags);
}

// Round 5
// 76.411 us; speedup vs baseline: 1.0250x; 1.0250x over previous
//
#include <hip/hip_runtime.h>

// Problem constants (fixed by setup_inputs): N=512 anchors, D=128 dims, K=16.
constexpr int NN = 512;
constexpr int DD = 128;
constexpr int KK = 16;
constexpr int GG = 2;           // anchors per block (one yad sweep serves both)
constexpr int NB = NN / GG;     // 256 blocks -> one per CU, all co-resident
constexpr int NT = 512;         // 8 waves: best measured config (77.8us round 3;
                                // 4-wave variant regressed to 78.3 -- latency
                                // hiding beats ds_read issue-pressure savings)
#define ALPHA 0.1f
#define MAGIC 0x5CA1AB1Eu       // != 0xAAAAAAAA harness poison, != 0

__global__ __launch_bounds__(NT) void area_loss_fused(
    const float* __restrict__ wid,
    const float* __restrict__ ken,
    const float* __restrict__ lrg,
    const float* __restrict__ sml,
    const float* __restrict__ yad,
    const int*   __restrict__ x,
    float*       __restrict__ out,
    float*       __restrict__ partial,   // d_ws
    unsigned*    __restrict__ flags)     // d_ws + NB floats
{
    __shared__ float    yi[GG][DD];        // the block's 2 anchor rows
    __shared__ float    d2[GG][NN];        // distances anchor->all j
    __shared__ unsigned mask[GG][NN / 32]; // membership bitsets
    __shared__ int      xl[GG][KK];        // staged x rows
    __shared__ float    posd[GG][KK];
    __shared__ int      pcnt[GG];
    __shared__ float    wsum[NT / 64];

    const int b = blockIdx.x;
    const int t = threadIdx.x;
    const int ibase = b * GG;

    // Hoisted hierarchical-term loads (threads 0..255): issue the four
    // HBM-cold global loads NOW so their ~900-cyc latency hides under the
    // distance phase; consumed only after the first __syncthreads sections.
    float hw = 0.f, hk = 0.f, hl = 0.f, hs = 0.f;
    if (t < GG * DD) {
        size_t idx = (size_t)ibase * DD + t;
        hw = wid[idx]; hk = ken[idx]; hl = lrg[idx]; hs = sml[idx];
    }

    // Stage anchors (float4), x rows; init masks/counters.
    if (t < GG * DD / 4)
        ((float4*)yi)[t] = ((const float4*)(yad + (size_t)ibase * DD))[t];
    if (t < GG * NN / 32) ((unsigned*)mask)[t] = 0u;
    if (t < GG * KK)      ((int*)xl)[t] = x[ibase * KK + t];
    if (t < GG)           pcnt[t] = 0;
    __syncthreads();

    // Membership bitmasks (duplicates collapse, matching reference scatter).
    if (t < GG * KK) {
        int a = t / KK;
        int j = xl[a][t % KK];
        atomicOr(&mask[a][j >> 5], 1u << (j & 31));
    }

    // Distances: thread t owns row j=t (1 row/thread, 8 waves for latency
    // hiding). yi read as float4 -> ds_read_b128, same-address broadcast.
    {
        const float4* row = (const float4*)(yad + (size_t)t * DD);
        float a0 = 0.f, a1 = 0.f;
#pragma unroll
        for (int c = 0; c < DD / 4; ++c) {
            float4 v  = row[c];
            float4 y0 = ((const float4*)yi[0])[c];
            float4 y1 = ((const float4*)yi[1])[c];
            float e;
            e = v.x - y0.x; a0 += e * e;
            e = v.y - y0.y; a0 += e * e;
            e = v.z - y0.z; a0 += e * e;
            e = v.w - y0.w; a0 += e * e;
            e = v.x - y1.x; a1 += e * e;
            e = v.y - y1.y; a1 += e * e;
            e = v.z - y1.z; a1 += e * e;
            e = v.w - y1.w; a1 += e * e;
        }
        d2[0][t] = a0;
        d2[1][t] = a1;
    }
    __syncthreads();

    // Pos-set gather: first occurrence only (dedup), j != anchor.
    if (t < GG * KK) {
        int a = t / KK, e = t % KK;
        int j = xl[a][e];
        bool ok = (j != ibase + a);
        for (int q = 0; q < e && ok; ++q)
            if (xl[a][q] == j) ok = false;
        if (ok) {
            int p = atomicAdd(&pcnt[a], 1);
            posd[a][p] = d2[a][j];
        }
    }
    __syncthreads();

    float acc = 0.f;

    // Triplet hinge: thread t owns neg-candidate k=t for each anchor.
#pragma unroll
    for (int a = 0; a < GG; ++a) {
        const int ia = ibase + a;
        const int P  = pcnt[a];
        if (t != ia && !((mask[a][t >> 5] >> (t & 31)) & 1u)) {
            float dk = d2[a][t];
            for (int p = 0; p < P; ++p)
                acc += fmaxf(posd[a][p] - dk + ALPHA, 0.f);
        }
    }

    // Hierarchical term (values already loaded at kernel top).
    if (t < GG * DD) {
        float y = ((float*)yi)[t];
        float p0 = hw - hk, p1 = hw - hl, p2 = hl - hs, p3 = hs - y;
        acc += p0 * p0 + p1 * p1 + p2 * p2 + p3 * p3;
    }

    // Block reduction: shuffle within wave-64, LDS across 8 waves.
    for (int off = 32; off; off >>= 1) acc += __shfl_down(acc, off, 64);
    if ((t & 63) == 0) wsum[t >> 6] = acc;
    __syncthreads();

    if (b != 0) {
        if (t == 0) {
            float s = 0.f;
#pragma unroll
            for (int w = 0; w < NT / 64; ++w) s += wsum[w];
            partial[b] = s;
            // Release: partial[b] visible device-wide before flag flips.
            __hip_atomic_store(&flags[b], MAGIC, __ATOMIC_RELEASE,
                               __HIP_MEMORY_SCOPE_AGENT);
        }
    } else {
        // Block 0: own sum, then gather the other 255 partials via flag spin.
        float mine = 0.f;
        if (t == 0) {
#pragma unroll
            for (int w = 0; w < NT / 64; ++w) mine += wsum[w];
        }
        __syncthreads();  // t0 done with wsum before reuse

        float other = 0.f;
        if (t >= 1 && t < NB) {
            while (__hip_atomic_load(&flags[t], __ATOMIC_ACQUIRE,
                                     __HIP_MEMORY_SCOPE_AGENT) != MAGIC) {
                __builtin_amdgcn_s_sleep(1);
            }
            other = partial[t];
        }
        float tot = mine + other;
        for (int off = 32; off; off >>= 1) tot += __shfl_down(tot, off, 64);
        if ((t & 63) == 0) wsum[t >> 6] = tot;
        __syncthreads();
        if (t == 0) {
            float s = 0.f;
#pragma unroll
            for (int w = 0; w < NT / 64; ++w) s += wsum[w];
            out[0] = s;
        }
    }
}

extern "C" void kernel_launch(void* const* d_in, const int* in_sizes, int n_in,
                              void* d_out, int out_size, void* d_ws, size_t ws_size,
                              hipStream_t stream) {
    const float* wid = (const float*)d_in[0];
    const float* ken = (const float*)d_in[1];
    const float* lrg = (const float*)d_in[2];
    const float* sml = (const float*)d_in[3];
    const float* yad = (const float*)d_in[4];
    const int*   x   = (const int*)d_in[5];
    float*    out     = (float*)d_out;
    float*    partial = (float*)d_ws;              // NB floats
    unsigned* flags   = (unsigned*)(partial + NB); // NB words; poison != MAGIC

    area_loss_fused<<<NB, NT, 0, stream>>>(wid, ken, lrg, sml, yad, x,
                                           out, partial, flags);
}